// Round 1
// 443.739 us; speedup vs baseline: 1.2457x; 1.2457x over previous
//
#include <hip/hip_runtime.h>
#include <math.h>

#define VV 50257
#define Dm 128
#define NN 256
#define RESN 4096
#define SEQ 512
#define TOK 1024  // B*S

using f32x4_t = __attribute__((ext_vector_type(4))) float;
using s16x8_t = __attribute__((ext_vector_type(8))) short;
using u16x4_t = __attribute__((ext_vector_type(4))) unsigned short;
using i32x4_t = __attribute__((ext_vector_type(4))) int;

static __device__ __forceinline__ unsigned short f2bf(float f) {
    unsigned u = __builtin_bit_cast(unsigned, f);
    u += 0x7fffu + ((u >> 16) & 1u);
    return (unsigned short)(u >> 16);
}

// ---------------- pack: invwl/Bp/ac/as float4 tables, transposed cw/opr/opi, LUT ----------------
__global__ void pack_kernel(const float* __restrict__ W, const float* __restrict__ Bp,
                            const float* __restrict__ ac, const float* __restrict__ as_,
                            const float* __restrict__ cw, const float* __restrict__ opr,
                            const float* __restrict__ opi,
                            float4* __restrict__ packed, float* __restrict__ cwT,
                            float* __restrict__ oprT, float* __restrict__ opiT,
                            float2* __restrict__ lutg) {
    int tid = blockIdx.x * 256 + threadIdx.x;  // 0..65535
    int l = tid >> 15;
    int rem = tid & 32767;
    {   // packed[l][d][n]
        int d = rem >> 8, n = rem & 255;
        int src = (l * NN + n) * Dm + d;
        float4 pk;
        pk.x = 1.0f / (1.0f + fabsf(W[src]));
        pk.y = Bp[src];
        pk.z = ac[src];
        pk.w = as_[src];
        packed[tid] = pk;
    }
    {   // cwT[l][k][d] = cw[l][d][k]
        int k = rem >> 7, d = rem & 127;
        cwT[tid] = cw[(l * Dm + d) * (2 * Dm) + k];
    }
    {   // oprT[l][n][d] = opr[l][d][n]
        int n = rem >> 7, d = rem & 127;
        oprT[tid] = opr[(l * Dm + d) * NN + n];
        opiT[tid] = opi[(l * Dm + d) * NN + n];
    }
    if (tid < RESN) {
        float ang = (float)tid * (float)(6.283185307179586476925286766559 / 4096.0);
        lutg[tid] = make_float2(sinf(ang), cosf(ang));
    }
}

// ---------------- one-off: fp32 Wr/Wi -> bf16 (removes f2bf from final's hot loop) ----------------
__global__ void wconv_kernel(const float* __restrict__ Wr, const float* __restrict__ Wi,
                             unsigned short* __restrict__ Wr_bf,
                             unsigned short* __restrict__ Wi_bf) {
    int gid = blockIdx.x * 256 + threadIdx.x;
    int base = gid * 4;
    if (base < VV * Dm) {
        float4 r = *(const float4*)(Wr + base);
        float4 w = *(const float4*)(Wi + base);
        *(u16x4_t*)(Wr_bf + base) = (u16x4_t){f2bf(r.x), f2bf(r.y), f2bf(r.z), f2bf(r.w)};
        *(u16x4_t*)(Wi_bf + base) = (u16x4_t){f2bf(w.x), f2bf(w.y), f2bf(w.z), f2bf(w.w)};
    }
}

// ---------------- embedding gather: x[t][0:256] = emb[ids[t]] ----------------
__global__ void embed_kernel(const int* __restrict__ ids, const float* __restrict__ emb,
                             float* __restrict__ x) {
    int t = blockIdx.x;
    int k = threadIdx.x;
    x[t * 256 + k] = emb[(size_t)ids[t] * 256 + k];
}

// ---------------- xc = x @ cw[l].T + cb[l] : (1024 x 128), K=256 ----------------
__global__ void xc_kernel(const float* __restrict__ x, const float* __restrict__ cwT,
                          const float* __restrict__ cb, float* __restrict__ xc, int l) {
    __shared__ float xs[2][256];
    int tid = threadIdx.x;
    int t0 = blockIdx.x * 2;
    xs[0][tid] = x[t0 * 256 + tid];
    xs[1][tid] = x[(t0 + 1) * 256 + tid];
    __syncthreads();
    int j = tid >> 7, d = tid & 127;
    const float* cwb = cwT + l * 32768;
    float acc = 0.f;
#pragma unroll 8
    for (int k = 0; k < 256; k++) acc = fmaf(xs[j][k], cwb[k * 128 + d], acc);
    xc[(t0 + j) * 128 + d] = acc + cb[l * 128 + d];
}

// ---------------- theta/LUT/reduce over d: partial cos_sum/sin_sum ----------------
// grid (256 token-groups of 4, 2 d-halves); thread = n
__global__ void __launch_bounds__(256) theta_kernel(const float* __restrict__ xc,
                                                    const float4* __restrict__ packed,
                                                    const float2* __restrict__ lutg,
                                                    float* __restrict__ pr_part,
                                                    float* __restrict__ pi_part, int l) {
    __shared__ float2 lut[RESN];
    __shared__ float xcs[4][64];
    int tid = threadIdx.x;
    int t0 = blockIdx.x * 4;
    int dh = blockIdx.y;
    // copy LUT global->LDS (float4 = 2 entries)
    const float4* lg = (const float4*)lutg;
    float4* ldst = (float4*)lut;
#pragma unroll
    for (int i = 0; i < 8; i++) ldst[tid + i * 256] = lg[tid + i * 256];
    {
        int j = tid >> 6, i = tid & 63;
        xcs[j][i] = xc[(t0 + j) * 128 + dh * 64 + i];
    }
    __syncthreads();
    float tv[4];
#pragma unroll
    for (int j = 0; j < 4; j++) {
        int s = (t0 + j) & (SEQ - 1);
        tv[j] = (float)s * 1.61803398874989485f;  // PHI
    }
    const float4* pk = packed + ((size_t)(l * Dm + dh * 64)) * NN + tid;
    float cs[4] = {0, 0, 0, 0}, sn[4] = {0, 0, 0, 0};
    const float SC = (float)(4096.0 / 6.283185307179586476925286766559);
    for (int d = 0; d < 64; d++) {
        float4 p = pk[(size_t)d * NN];
#pragma unroll
        for (int j = 0; j < 4; j++) {
            float th = fmaf(xcs[j][d], p.x, p.y) + tv[j];
            int idx = ((int)floorf(th * SC)) & (RESN - 1);
            float2 scv = lut[idx];
            cs[j] = fmaf(scv.y, p.z, cs[j]);  // cos * attn_cos
            sn[j] = fmaf(scv.x, p.w, sn[j]);  // sin * attn_sin
        }
    }
#pragma unroll
    for (int j = 0; j < 4; j++) {
        pr_part[(size_t)(dh * TOK + t0 + j) * NN + tid] = cs[j];
        pi_part[(size_t)(dh * TOK + t0 + j) * NN + tid] = sn[j];
    }
}

// ---------------- out-proj: x_new = silu(sum @ op.T), writes [xr|xi] layout + bf16 copy ----------------
__global__ void proj_kernel(const float* __restrict__ pr_part, const float* __restrict__ pi_part,
                            const float* __restrict__ oprT, const float* __restrict__ opiT,
                            float* __restrict__ x, unsigned short* __restrict__ x_bf, int l) {
    __shared__ float prs[4][256], pis[4][256];
    int tid = threadIdx.x;
    int t0 = blockIdx.x * 4;
#pragma unroll
    for (int i = 0; i < 4; i++) {
        prs[i][tid] = pr_part[(size_t)(t0 + i) * 256 + tid] +
                      pr_part[(size_t)(TOK + t0 + i) * 256 + tid];
        pis[i][tid] = pi_part[(size_t)(t0 + i) * 256 + tid] +
                      pi_part[(size_t)(TOK + t0 + i) * 256 + tid];
    }
    __syncthreads();
    int g = tid >> 7, d = tid & 127;
    const float* wb = (g == 0 ? oprT : opiT) + l * 32768;
    const float(*ps)[256] = (g == 0) ? prs : pis;
    float acc[4] = {0, 0, 0, 0};
    for (int n = 0; n < 256; n++) {
        float wv = wb[n * 128 + d];
#pragma unroll
        for (int j = 0; j < 4; j++) acc[j] = fmaf(ps[j][n], wv, acc[j]);
    }
#pragma unroll
    for (int j = 0; j < 4; j++) {
        float v = acc[j];
        float s = v / (1.0f + expf(-v));  // silu
        x[(t0 + j) * 256 + g * 128 + d] = s;
        x_bf[(t0 + j) * 256 + g * 128 + d] = f2bf(s);  // bf16 copy for final GEMM A
    }
}

// ---------------- final complex GEMM + magnitude ----------------
// A = x_bf (1024 x 256 = [xr|xi]); B1 = [Wr|-Wi], B2 = [Wi|Wr] from precomputed bf16
// out[t][v] = sqrt(lr^2 + li^2 + 1e-8)
__global__ void __launch_bounds__(256, 2) final_kernel(const unsigned short* __restrict__ x_bf,
                                                       const unsigned short* __restrict__ Wr_bf,
                                                       const unsigned short* __restrict__ Wi_bf,
                                                       float* __restrict__ out) {
    __shared__ unsigned short As[128 * 72];
    __shared__ unsigned short B1s[128 * 72];
    __shared__ unsigned short B2s[128 * 72];
    int tid = threadIdx.x;
    // XCD-contiguous swizzle, t fastest (bijective: 3144 = 8*393).
    // Round-robin dispatch sends wg%8 to XCD (wg%8); each XCD then owns a
    // contiguous wgid range where the 8 t-blocks sharing a v-chunk are
    // consecutive -> W chunk L2-resident, fetched ~once from HBM.
    int wg = blockIdx.x;
    int wgid = (wg & 7) * 393 + (wg >> 3);
    int vb = wgid >> 3, tb = wgid & 7;
    int v0 = vb * 128;
    int t0 = tb * 128;
    int wave = tid >> 6, lane = tid & 63;
    int wm = wave >> 1, wn = wave & 1;
    int quad = lane >> 4, t16 = lane & 15;

    f32x4_t accR[4][4], accI[4][4];
#pragma unroll
    for (int im = 0; im < 4; im++)
#pragma unroll
        for (int in = 0; in < 4; in++) {
            accR[im][in] = (f32x4_t){0.f, 0.f, 0.f, 0.f};
            accI[im][in] = (f32x4_t){0.f, 0.f, 0.f, 0.f};
        }

    const i32x4_t NEG = {(int)0x80008000, (int)0x80008000, (int)0x80008000, (int)0x80008000};

    for (int kc = 0; kc < 4; kc++) {
        __syncthreads();  // previous compute finished before overwriting LDS
        int kbase = (kc & 1) * 64;
        const unsigned short* b1src = (kc < 2) ? Wr_bf : Wi_bf;  // kc>=2: -Wi (sign-xor below)
        const unsigned short* b2src = (kc < 2) ? Wi_bf : Wr_bf;
        // --- stage A + B chunks: pure bf16 16B copies, no conversion VALU ---
#pragma unroll
        for (int i = 0; i < 4; i++) {
            int idx = tid + i * 256;          // 0..1023
            int row = idx >> 3, c8 = idx & 7; // 128 rows x 8 slots of 8 bf16
            i32x4_t a = *(const i32x4_t*)(x_bf + (size_t)(t0 + row) * 256 + kc * 64 + c8 * 8);
            *(i32x4_t*)(As + row * 72 + c8 * 8) = a;
            int v = v0 + row;
            if (v >= VV) v = VV - 1;
            i32x4_t b1 = *(const i32x4_t*)(b1src + (size_t)v * 128 + kbase + c8 * 8);
            i32x4_t b2 = *(const i32x4_t*)(b2src + (size_t)v * 128 + kbase + c8 * 8);
            if (kc >= 2) b1 ^= NEG;  // bf16 negate = sign-bit xor (RNE is sign-symmetric)
            *(i32x4_t*)(B1s + row * 72 + c8 * 8) = b1;
            *(i32x4_t*)(B2s + row * 72 + c8 * 8) = b2;
        }
        __syncthreads();
        // --- compute: 2 k-steps of 32 ---
#pragma unroll
        for (int ks = 0; ks < 2; ks++) {
            int kofs = ks * 32 + quad * 8;
            s16x8_t af[4], bR[4], bI[4];
#pragma unroll
            for (int im = 0; im < 4; im++)
                af[im] = *(const s16x8_t*)(As + (wm * 64 + im * 16 + t16) * 72 + kofs);
#pragma unroll
            for (int in = 0; in < 4; in++) {
                bR[in] = *(const s16x8_t*)(B1s + (wn * 64 + in * 16 + t16) * 72 + kofs);
                bI[in] = *(const s16x8_t*)(B2s + (wn * 64 + in * 16 + t16) * 72 + kofs);
            }
#pragma unroll
            for (int im = 0; im < 4; im++)
#pragma unroll
                for (int in = 0; in < 4; in++) {
                    accR[im][in] = __builtin_amdgcn_mfma_f32_16x16x32_bf16(
                        af[im], bR[in], accR[im][in], 0, 0, 0);
                    accI[im][in] = __builtin_amdgcn_mfma_f32_16x16x32_bf16(
                        af[im], bI[in], accI[im][in], 0, 0, 0);
                }
        }
    }
    // --- epilogue: magnitude + store (C/D: col=lane&15 -> v, row=quad*4+reg -> t) ---
#pragma unroll
    for (int im = 0; im < 4; im++) {
        int tbase = t0 + wm * 64 + im * 16 + quad * 4;
#pragma unroll
        for (int in = 0; in < 4; in++) {
            int v = v0 + wn * 64 + in * 16 + t16;
            if (v < VV) {
#pragma unroll
                for (int r = 0; r < 4; r++) {
                    float lr = accR[im][in][r];
                    float li = accI[im][in][r];
                    out[(size_t)(tbase + r) * VV + v] = sqrtf(fmaf(lr, lr, fmaf(li, li, 1e-8f)));
                }
            }
        }
    }
}

extern "C" void kernel_launch(void* const* d_in, const int* in_sizes, int n_in,
                              void* d_out, int out_size, void* d_ws, size_t ws_size,
                              hipStream_t stream) {
    const int* ids   = (const int*)d_in[0];
    const float* emb = (const float*)d_in[1];
    const float* cw  = (const float*)d_in[2];
    const float* cb  = (const float*)d_in[3];
    const float* W   = (const float*)d_in[4];
    const float* Bp  = (const float*)d_in[5];
    const float* ac  = (const float*)d_in[6];
    const float* as_ = (const float*)d_in[7];
    const float* opr = (const float*)d_in[8];
    const float* opi = (const float*)d_in[9];
    const float* Wr  = (const float*)d_in[10];
    const float* Wi  = (const float*)d_in[11];
    float* out = (float*)d_out;

    char* ws = (char*)d_ws;
    float*  x       = (float*)(ws);                          // 1 MB (1024x256)
    float*  xc      = (float*)(ws + (1u << 20));             // 512 KB
    float*  pr_part = (float*)(ws + (2u << 20));             // 2 MB (2x1024x256)
    float*  pi_part = (float*)(ws + (4u << 20));             // 2 MB
    float4* packed  = (float4*)(ws + (6u << 20));            // 1 MB (2x128x256 float4)
    float*  cwT     = (float*)(ws + (7u << 20));             // 256 KB
    float*  oprT    = (float*)(ws + (7u << 20) + (256u << 10));
    float*  opiT    = (float*)(ws + (7u << 20) + (512u << 10));
    float2* lutg    = (float2*)(ws + (7u << 20) + (768u << 10));  // 32 KB
    unsigned short* x_bf  = (unsigned short*)(ws + (8u  << 20));  // 512 KB (1024x256 bf16)
    unsigned short* Wr_bf = (unsigned short*)(ws + (9u  << 20));  // 12.27 MB (50257x128 bf16)
    unsigned short* Wi_bf = (unsigned short*)(ws + (22u << 20));  // 12.27 MB

    pack_kernel<<<256, 256, 0, stream>>>(W, Bp, ac, as_, cw, opr, opi,
                                         packed, cwT, oprT, opiT, lutg);
    wconv_kernel<<<(VV * Dm / 4 + 255) / 256, 256, 0, stream>>>(Wr, Wi, Wr_bf, Wi_bf);
    embed_kernel<<<TOK, 256, 0, stream>>>(ids, emb, x);
    for (int l = 0; l < 2; l++) {
        xc_kernel<<<TOK / 2, 256, 0, stream>>>(x, cwT, cb, xc, l);
        theta_kernel<<<dim3(TOK / 4, 2), 256, 0, stream>>>(xc, packed, lutg,
                                                           pr_part, pi_part, l);
        proj_kernel<<<TOK / 4, 256, 0, stream>>>(pr_part, pi_part, oprT, opiT, x, x_bf, l);
    }
    final_kernel<<<dim3(8 * 393), 256, 0, stream>>>(x_bf, Wr_bf, Wi_bf, out);
}

// Round 3
// 431.100 us; speedup vs baseline: 1.2822x; 1.0293x over previous
//
#include <hip/hip_runtime.h>
#include <math.h>

#define VV 50257
#define Dm 128
#define NN 256
#define RESN 4096
#define SEQ 512
#define TOK 1024  // B*S

using f32x4_t = __attribute__((ext_vector_type(4))) float;
using s16x8_t = __attribute__((ext_vector_type(8))) short;
using u16x4_t = __attribute__((ext_vector_type(4))) unsigned short;

static __device__ __forceinline__ unsigned short f2bf(float f) {
    unsigned u = __builtin_bit_cast(unsigned, f);
    u += 0x7fffu + ((u >> 16) & 1u);
    return (unsigned short)(u >> 16);
}

// async global->LDS, 16B per lane; LDS dest = uniform base + lane*16 (HW rule)
static __device__ __forceinline__ void gload16(const unsigned short* g, unsigned short* l) {
    __builtin_amdgcn_global_load_lds(
        (const __attribute__((address_space(1))) unsigned int*)g,
        (__attribute__((address_space(3))) unsigned int*)l, 16, 0, 0);
}

// ---------------- pack: invwl/Bp/ac/as float4 tables, transposed cw/opr/opi, LUT ----------------
__global__ void pack_kernel(const float* __restrict__ W, const float* __restrict__ Bp,
                            const float* __restrict__ ac, const float* __restrict__ as_,
                            const float* __restrict__ cw, const float* __restrict__ opr,
                            const float* __restrict__ opi,
                            float4* __restrict__ packed, float* __restrict__ cwT,
                            float* __restrict__ oprT, float* __restrict__ opiT,
                            float2* __restrict__ lutg) {
    int tid = blockIdx.x * 256 + threadIdx.x;  // 0..65535
    int l = tid >> 15;
    int rem = tid & 32767;
    {   // packed[l][d][n]
        int d = rem >> 8, n = rem & 255;
        int src = (l * NN + n) * Dm + d;
        float4 pk;
        pk.x = 1.0f / (1.0f + fabsf(W[src]));
        pk.y = Bp[src];
        pk.z = ac[src];
        pk.w = as_[src];
        packed[tid] = pk;
    }
    {   // cwT[l][k][d] = cw[l][d][k]
        int k = rem >> 7, d = rem & 127;
        cwT[tid] = cw[(l * Dm + d) * (2 * Dm) + k];
    }
    {   // oprT[l][n][d] = opr[l][d][n]
        int n = rem >> 7, d = rem & 127;
        oprT[tid] = opr[(l * Dm + d) * NN + n];
        opiT[tid] = opi[(l * Dm + d) * NN + n];
    }
    if (tid < RESN) {
        float ang = (float)tid * (float)(6.283185307179586476925286766559 / 4096.0);
        lutg[tid] = make_float2(sinf(ang), cosf(ang));
    }
}

// ---------------- one-off: fp32 Wr/Wi -> bf16 ----------------
__global__ void wconv_kernel(const float* __restrict__ Wr, const float* __restrict__ Wi,
                             unsigned short* __restrict__ Wr_bf,
                             unsigned short* __restrict__ Wi_bf) {
    int gid = blockIdx.x * 256 + threadIdx.x;
    int base = gid * 4;
    if (base < VV * Dm) {
        float4 r = *(const float4*)(Wr + base);
        float4 w = *(const float4*)(Wi + base);
        *(u16x4_t*)(Wr_bf + base) = (u16x4_t){f2bf(r.x), f2bf(r.y), f2bf(r.z), f2bf(r.w)};
        *(u16x4_t*)(Wi_bf + base) = (u16x4_t){f2bf(w.x), f2bf(w.y), f2bf(w.z), f2bf(w.w)};
    }
}

// ---------------- embedding gather: x[t][0:256] = emb[ids[t]] ----------------
__global__ void embed_kernel(const int* __restrict__ ids, const float* __restrict__ emb,
                             float* __restrict__ x) {
    int t = blockIdx.x;
    int k = threadIdx.x;
    x[t * 256 + k] = emb[(size_t)ids[t] * 256 + k];
}

// ---------------- xc = x @ cw[l].T + cb[l] : (1024 x 128), K=256 ----------------
__global__ void xc_kernel(const float* __restrict__ x, const float* __restrict__ cwT,
                          const float* __restrict__ cb, float* __restrict__ xc, int l) {
    __shared__ float xs[2][256];
    int tid = threadIdx.x;
    int t0 = blockIdx.x * 2;
    xs[0][tid] = x[t0 * 256 + tid];
    xs[1][tid] = x[(t0 + 1) * 256 + tid];
    __syncthreads();
    int j = tid >> 7, d = tid & 127;
    const float* cwb = cwT + l * 32768;
    float acc = 0.f;
#pragma unroll 8
    for (int k = 0; k < 256; k++) acc = fmaf(xs[j][k], cwb[k * 128 + d], acc);
    xc[(t0 + j) * 128 + d] = acc + cb[l * 128 + d];
}

// ---------------- theta/LUT/reduce over d: partial cos_sum/sin_sum ----------------
// grid (256 token-groups of 4, 2 d-halves); thread = n
__global__ void __launch_bounds__(256) theta_kernel(const float* __restrict__ xc,
                                                    const float4* __restrict__ packed,
                                                    const float2* __restrict__ lutg,
                                                    float* __restrict__ pr_part,
                                                    float* __restrict__ pi_part, int l) {
    __shared__ float2 lut[RESN];
    __shared__ float xcs[4][64];
    int tid = threadIdx.x;
    int t0 = blockIdx.x * 4;
    int dh = blockIdx.y;
    // copy LUT global->LDS (float4 = 2 entries)
    const float4* lg = (const float4*)lutg;
    float4* ldst = (float4*)lut;
#pragma unroll
    for (int i = 0; i < 8; i++) ldst[tid + i * 256] = lg[tid + i * 256];
    {
        int j = tid >> 6, i = tid & 63;
        xcs[j][i] = xc[(t0 + j) * 128 + dh * 64 + i];
    }
    __syncthreads();
    float tv[4];
#pragma unroll
    for (int j = 0; j < 4; j++) {
        int s = (t0 + j) & (SEQ - 1);
        tv[j] = (float)s * 1.61803398874989485f;  // PHI
    }
    const float4* pk = packed + ((size_t)(l * Dm + dh * 64)) * NN + tid;
    float cs[4] = {0, 0, 0, 0}, sn[4] = {0, 0, 0, 0};
    const float SC = (float)(4096.0 / 6.283185307179586476925286766559);
    for (int d = 0; d < 64; d++) {
        float4 p = pk[(size_t)d * NN];
#pragma unroll
        for (int j = 0; j < 4; j++) {
            float th = fmaf(xcs[j][d], p.x, p.y) + tv[j];
            int idx = ((int)floorf(th * SC)) & (RESN - 1);
            float2 scv = lut[idx];
            cs[j] = fmaf(scv.y, p.z, cs[j]);  // cos * attn_cos
            sn[j] = fmaf(scv.x, p.w, sn[j]);  // sin * attn_sin
        }
    }
#pragma unroll
    for (int j = 0; j < 4; j++) {
        pr_part[(size_t)(dh * TOK + t0 + j) * NN + tid] = cs[j];
        pi_part[(size_t)(dh * TOK + t0 + j) * NN + tid] = sn[j];
    }
}

// ---------------- out-proj: x_new = silu(sum @ op.T), writes [xr|xi] layout + bf16 copy ----------------
__global__ void proj_kernel(const float* __restrict__ pr_part, const float* __restrict__ pi_part,
                            const float* __restrict__ oprT, const float* __restrict__ opiT,
                            float* __restrict__ x, unsigned short* __restrict__ x_bf, int l) {
    __shared__ float prs[4][256], pis[4][256];
    int tid = threadIdx.x;
    int t0 = blockIdx.x * 4;
#pragma unroll
    for (int i = 0; i < 4; i++) {
        prs[i][tid] = pr_part[(size_t)(t0 + i) * 256 + tid] +
                      pr_part[(size_t)(TOK + t0 + i) * 256 + tid];
        pis[i][tid] = pi_part[(size_t)(t0 + i) * 256 + tid] +
                      pi_part[(size_t)(TOK + t0 + i) * 256 + tid];
    }
    __syncthreads();
    int g = tid >> 7, d = tid & 127;
    const float* wb = (g == 0 ? oprT : opiT) + l * 32768;
    const float(*ps)[256] = (g == 0) ? prs : pis;
    float acc[4] = {0, 0, 0, 0};
    for (int n = 0; n < 256; n++) {
        float wv = wb[n * 128 + d];
#pragma unroll
        for (int j = 0; j < 4; j++) acc[j] = fmaf(ps[j][n], wv, acc[j]);
    }
#pragma unroll
    for (int j = 0; j < 4; j++) {
        float v = acc[j];
        float s = v / (1.0f + expf(-v));  // silu
        x[(t0 + j) * 256 + g * 128 + d] = s;
        x_bf[(t0 + j) * 256 + g * 128 + d] = f2bf(s);  // bf16 copy for final GEMM A
    }
}

// ---------------- final complex GEMM + magnitude (2-phase pipelined, gload_lds, swizzled) -----
// 4-real-GEMM decomposition: RR=xr·WrT, II=xi·WiT, IR=xi·WrT, RI=xr·WiT
// lr = RR-II, li = IR+RI, out = sqrt(lr^2+li^2+1e-8)
// Block: 256 thr = 4 waves (wm=t half, wn=v half); tile 128t x 64v; K-chunk 32, 4 phases.
// LDS/buffer: Ar[128][32] | Ai[128][32] | Wr[64][32] | Wi[64][32] bf16 = 24KB; x2 dbuf = 48KB.
// Rows are 64B linear (gload_lds requirement); bank-conflict-free via chunk XOR swizzle:
//   write side: per-lane GLOBAL source chunk = (lane&3) ^ ((lane>>3)&3)   [LDS stays linear]
//   read  side: LDS chunk = quad ^ ((t16>>1)&3)
// -> LDS(r,c) holds global chunk c^((r>>1)&3); reader at row R (R&15=t16) reads chunk
//    quad^rsw which holds global chunk quad. Each ds_read_b128 hits every bank exactly 8x.
__global__ void __launch_bounds__(256, 2) final_kernel(const unsigned short* __restrict__ x_bf,
                                                       const unsigned short* __restrict__ Wr_bf,
                                                       const unsigned short* __restrict__ Wi_bf,
                                                       float* __restrict__ out) {
    __shared__ unsigned short lds[2][12288];  // 2 x 24KB
    int tid = threadIdx.x;
    // bijective XCD swizzle (6288 = 8*786), t fastest within an XCD's chunk:
    // 8 t-blocks of one v-chunk run back-to-back on one XCD -> W chunk L2-resident.
    int wg = blockIdx.x;
    int wp = (wg & 7) * 786 + (wg >> 3);
    int vb = wp >> 3, tb = wp & 7;
    int v0 = vb * 64, t0 = tb * 128;

    int wv = tid >> 6, lane = tid & 63;
    int wm = wv >> 1, wn = wv & 1;
    int quad = lane >> 4, t16 = lane & 15;

    // ---- staging lane mapping (per-lane global source, linear LDS dest) ----
    int r_loc = lane >> 2;                       // row within a 16-row gload instruction
    int csw = (lane & 3) ^ ((lane >> 3) & 3);    // pre-swizzled source chunk (16B units)
    const unsigned short* srcA0 = x_bf + (size_t)(t0 + 32 * wv + r_loc) * 256 + csw * 8;
    const unsigned short* srcA1 = srcA0 + 16 * 256;
    int vv_ = v0 + 16 * wv + r_loc;
    if (vv_ > VV - 1) vv_ = VV - 1;              // clamp OOB v rows (dup loads, never stored)
    const unsigned short* srcWr = Wr_bf + (size_t)vv_ * 128 + csw * 8;
    const unsigned short* srcWi = Wi_bf + (size_t)vv_ * 128 + csw * 8;

    // ---- read-side constants ----
    int rsw = (t16 >> 1) & 3;
    int rdA = (wm * 64 + t16) * 32 + ((quad ^ rsw) << 3);  // +im*512; Ai region +4096
    int rdB = (wn * 32 + t16) * 32 + ((quad ^ rsw) << 3);  // +in*512; Wr +8192, Wi +10240

    f32x4_t aRR[4][2], aII[4][2], aIR[4][2], aRI[4][2];
#pragma unroll
    for (int im = 0; im < 4; im++)
#pragma unroll
        for (int in = 0; in < 2; in++) {
            aRR[im][in] = (f32x4_t){0.f, 0.f, 0.f, 0.f};
            aII[im][in] = (f32x4_t){0.f, 0.f, 0.f, 0.f};
            aIR[im][in] = (f32x4_t){0.f, 0.f, 0.f, 0.f};
            aRI[im][in] = (f32x4_t){0.f, 0.f, 0.f, 0.f};
        }

    // 6 gload_lds per wave per phase: 2x Ar, 2x Ai, 1x Wr, 1x Wi
#define STAGE(b, kc)                                                             \
    {                                                                            \
        const int ko = (kc) * 32;                                                \
        unsigned short* bb = lds[(b)];                                           \
        gload16(srcA0 + ko, bb + wv * 1024);                                     \
        gload16(srcA1 + ko, bb + wv * 1024 + 512);                               \
        gload16(srcA0 + 128 + ko, bb + 4096 + wv * 1024);                        \
        gload16(srcA1 + 128 + ko, bb + 4096 + wv * 1024 + 512);                  \
        gload16(srcWr + ko, bb + 8192 + wv * 512);                               \
        gload16(srcWi + ko, bb + 10240 + wv * 512);                              \
    }

    STAGE(0, 0);  // prologue: 6 in flight
#pragma unroll
    for (int kc = 0; kc < 4; kc++) {
        if (kc < 3) {
            STAGE((kc + 1) & 1, kc + 1);                      // 12 in flight
            asm volatile("s_waitcnt vmcnt(6)" ::: "memory");  // own current-buffer loads landed
        } else {
            asm volatile("s_waitcnt vmcnt(0)" ::: "memory");
        }
        __builtin_amdgcn_s_barrier();           // all waves' current-buffer loads landed
        __builtin_amdgcn_sched_barrier(0);      // pin ds_reads AFTER the cross-wave sync
        const unsigned short* B = lds[kc & 1];
        s16x8_t ar[4], ai[4], fr[2], fi[2];
#pragma unroll
        for (int im = 0; im < 4; im++) {
            ar[im] = *(const s16x8_t*)(B + rdA + im * 512);
            ai[im] = *(const s16x8_t*)(B + 4096 + rdA + im * 512);
        }
#pragma unroll
        for (int in = 0; in < 2; in++) {
            fr[in] = *(const s16x8_t*)(B + 8192 + rdB + in * 512);
            fi[in] = *(const s16x8_t*)(B + 10240 + rdB + in * 512);
        }
#pragma unroll
        for (int im = 0; im < 4; im++)
#pragma unroll
            for (int in = 0; in < 2; in++) {
                aRR[im][in] = __builtin_amdgcn_mfma_f32_16x16x32_bf16(ar[im], fr[in],
                                                                      aRR[im][in], 0, 0, 0);
                aII[im][in] = __builtin_amdgcn_mfma_f32_16x16x32_bf16(ai[im], fi[in],
                                                                      aII[im][in], 0, 0, 0);
                aIR[im][in] = __builtin_amdgcn_mfma_f32_16x16x32_bf16(ai[im], fr[in],
                                                                      aIR[im][in], 0, 0, 0);
                aRI[im][in] = __builtin_amdgcn_mfma_f32_16x16x32_bf16(ar[im], fi[in],
                                                                      aRI[im][in], 0, 0, 0);
            }
        __builtin_amdgcn_s_barrier();  // all reads of this buffer done before restage
    }
#undef STAGE

    // --- epilogue: complex combine + magnitude + store ---
#pragma unroll
    for (int im = 0; im < 4; im++) {
        int trow = t0 + wm * 64 + im * 16 + quad * 4;
#pragma unroll
        for (int in = 0; in < 2; in++) {
            int v = v0 + wn * 32 + in * 16 + t16;
            if (v < VV) {
#pragma unroll
                for (int r = 0; r < 4; r++) {
                    float lr = aRR[im][in][r] - aII[im][in][r];
                    float li = aIR[im][in][r] + aRI[im][in][r];
                    out[(size_t)(trow + r) * VV + v] = sqrtf(fmaf(lr, lr, fmaf(li, li, 1e-8f)));
                }
            }
        }
    }
}

extern "C" void kernel_launch(void* const* d_in, const int* in_sizes, int n_in,
                              void* d_out, int out_size, void* d_ws, size_t ws_size,
                              hipStream_t stream) {
    const int* ids   = (const int*)d_in[0];
    const float* emb = (const float*)d_in[1];
    const float* cw  = (const float*)d_in[2];
    const float* cb  = (const float*)d_in[3];
    const float* W   = (const float*)d_in[4];
    const float* Bp  = (const float*)d_in[5];
    const float* ac  = (const float*)d_in[6];
    const float* as_ = (const float*)d_in[7];
    const float* opr = (const float*)d_in[8];
    const float* opi = (const float*)d_in[9];
    const float* Wr  = (const float*)d_in[10];
    const float* Wi  = (const float*)d_in[11];
    float* out = (float*)d_out;

    char* ws = (char*)d_ws;
    float*  x       = (float*)(ws);                          // 1 MB (1024x256)
    float*  xc      = (float*)(ws + (1u << 20));             // 512 KB
    float*  pr_part = (float*)(ws + (2u << 20));             // 2 MB (2x1024x256)
    float*  pi_part = (float*)(ws + (4u << 20));             // 2 MB
    float4* packed  = (float4*)(ws + (6u << 20));            // 1 MB (2x128x256 float4)
    float*  cwT     = (float*)(ws + (7u << 20));             // 256 KB
    float*  oprT    = (float*)(ws + (7u << 20) + (256u << 10));
    float*  opiT    = (float*)(ws + (7u << 20) + (512u << 10));
    float2* lutg    = (float2*)(ws + (7u << 20) + (768u << 10));  // 32 KB
    unsigned short* x_bf  = (unsigned short*)(ws + (8u  << 20));  // 512 KB (1024x256 bf16)
    unsigned short* Wr_bf = (unsigned short*)(ws + (9u  << 20));  // 12.27 MB (50257x128 bf16)
    unsigned short* Wi_bf = (unsigned short*)(ws + (22u << 20));  // 12.27 MB

    pack_kernel<<<256, 256, 0, stream>>>(W, Bp, ac, as_, cw, opr, opi,
                                         packed, cwT, oprT, opiT, lutg);
    wconv_kernel<<<(VV * Dm / 4 + 255) / 256, 256, 0, stream>>>(Wr, Wi, Wr_bf, Wi_bf);
    embed_kernel<<<TOK, 256, 0, stream>>>(ids, emb, x);
    for (int l = 0; l < 2; l++) {
        xc_kernel<<<TOK / 2, 256, 0, stream>>>(x, cwT, cb, xc, l);
        theta_kernel<<<dim3(TOK / 4, 2), 256, 0, stream>>>(xc, packed, lutg,
                                                           pr_part, pi_part, l);
        proj_kernel<<<TOK / 4, 256, 0, stream>>>(pr_part, pi_part, oprT, opiT, x, x_bf, l);
    }
    final_kernel<<<dim3(786 * 8), 256, 0, stream>>>(x_bf, Wr_bf, Wi_bf, out);
}

// Round 4
// 420.265 us; speedup vs baseline: 1.3153x; 1.0258x over previous
//
#include <hip/hip_runtime.h>
#include <math.h>

#define VV 50257
#define Dm 128
#define NN 256
#define RESN 4096
#define SEQ 512
#define TOK 1024  // B*S

using f32x4_t = __attribute__((ext_vector_type(4))) float;
using s16x8_t = __attribute__((ext_vector_type(8))) short;
using u16x4_t = __attribute__((ext_vector_type(4))) unsigned short;

static __device__ __forceinline__ unsigned short f2bf(float f) {
    unsigned u = __builtin_bit_cast(unsigned, f);
    u += 0x7fffu + ((u >> 16) & 1u);
    return (unsigned short)(u >> 16);
}

// async global->LDS, 16B per lane; LDS dest = uniform base + lane*16 (HW rule)
static __device__ __forceinline__ void gload16(const unsigned short* g, unsigned short* l) {
    __builtin_amdgcn_global_load_lds(
        (const __attribute__((address_space(1))) unsigned int*)g,
        (__attribute__((address_space(3))) unsigned int*)l, 16, 0, 0);
}

// ---------------- pack: invwl/Bp/ac/as float4 tables, transposed cw/opr/opi, LUT ----------------
__global__ void pack_kernel(const float* __restrict__ W, const float* __restrict__ Bp,
                            const float* __restrict__ ac, const float* __restrict__ as_,
                            const float* __restrict__ cw, const float* __restrict__ opr,
                            const float* __restrict__ opi,
                            float4* __restrict__ packed, float* __restrict__ cwT,
                            float* __restrict__ oprT, float* __restrict__ opiT,
                            float2* __restrict__ lutg) {
    int tid = blockIdx.x * 256 + threadIdx.x;  // 0..65535
    int l = tid >> 15;
    int rem = tid & 32767;
    {   // packed[l][d][n]
        int d = rem >> 8, n = rem & 255;
        int src = (l * NN + n) * Dm + d;
        float4 pk;
        pk.x = 1.0f / (1.0f + fabsf(W[src]));
        pk.y = Bp[src];
        pk.z = ac[src];
        pk.w = as_[src];
        packed[tid] = pk;
    }
    {   // cwT[l][k][d] = cw[l][d][k]
        int k = rem >> 7, d = rem & 127;
        cwT[tid] = cw[(l * Dm + d) * (2 * Dm) + k];
    }
    {   // oprT[l][n][d] = opr[l][d][n]
        int n = rem >> 7, d = rem & 127;
        oprT[tid] = opr[(l * Dm + d) * NN + n];
        opiT[tid] = opi[(l * Dm + d) * NN + n];
    }
    if (tid < RESN) {
        float ang = (float)tid * (float)(6.283185307179586476925286766559 / 4096.0);
        lutg[tid] = make_float2(sinf(ang), cosf(ang));
    }
}

// ---------------- one-off: fp32 Wr/Wi -> bf16 ----------------
__global__ void wconv_kernel(const float* __restrict__ Wr, const float* __restrict__ Wi,
                             unsigned short* __restrict__ Wr_bf,
                             unsigned short* __restrict__ Wi_bf) {
    int gid = blockIdx.x * 256 + threadIdx.x;
    int base = gid * 4;
    if (base < VV * Dm) {
        float4 r = *(const float4*)(Wr + base);
        float4 w = *(const float4*)(Wi + base);
        *(u16x4_t*)(Wr_bf + base) = (u16x4_t){f2bf(r.x), f2bf(r.y), f2bf(r.z), f2bf(r.w)};
        *(u16x4_t*)(Wi_bf + base) = (u16x4_t){f2bf(w.x), f2bf(w.y), f2bf(w.z), f2bf(w.w)};
    }
}

// ---------------- fused middle: embed + 2x(xc -> theta/LUT-reduce -> proj) per token ----------------
// The whole per-layer chain is token-local, so one block owns 2 tokens end-to-end:
// x stays in LDS across layers; only x_bf (final-GEMM A operand) is written to global.
// Replaces embed + 2x{xc_kernel, theta_kernel, proj_kernel} (6 dispatches + 4MB round-trips).
__global__ void __launch_bounds__(256) mid_kernel(const int* __restrict__ ids,
                                                  const float* __restrict__ emb,
                                                  const float* __restrict__ cwT,
                                                  const float* __restrict__ cb,
                                                  const float4* __restrict__ packed,
                                                  const float2* __restrict__ lutg,
                                                  const float* __restrict__ oprT,
                                                  const float* __restrict__ opiT,
                                                  unsigned short* __restrict__ x_bf) {
    __shared__ float2 lut[RESN];        // 32 KB
    __shared__ float xs[2][256];        // x = [xr|xi] per token
    __shared__ float xcp[2][2][128];    // xc k-half partials
    __shared__ float xc_s[2][128];
    __shared__ float cs_s[2][256], sn_s[2][256];

    int tid = threadIdx.x;
    int t0 = blockIdx.x * 2;

    // LUT global->LDS (float4 = 2 entries)
    const float4* lg = (const float4*)lutg;
    float4* ldst = (float4*)lut;
#pragma unroll
    for (int i = 0; i < 8; i++) ldst[tid + i * 256] = lg[tid + i * 256];
    // embed gather
#pragma unroll
    for (int j = 0; j < 2; j++) xs[j][tid] = emb[(size_t)ids[t0 + j] * 256 + tid];
    __syncthreads();

    int h = tid >> 7, d = tid & 127;
    float tv[2];
#pragma unroll
    for (int j = 0; j < 2; j++) tv[j] = (float)((t0 + j) & (SEQ - 1)) * 1.61803398874989485f;
    const float SC = (float)(4096.0 / 6.283185307179586476925286766559);

    for (int l = 0; l < 2; l++) {
        // ---- xc = x @ cw[l].T + cb[l]  (k-halves split across thread groups) ----
        const float* cwb = cwT + l * 32768;
#pragma unroll
        for (int j = 0; j < 2; j++) {
            float acc = 0.f;
#pragma unroll 8
            for (int k = h * 128; k < h * 128 + 128; k++)
                acc = fmaf(xs[j][k], cwb[k * 128 + d], acc);
            xcp[j][h][d] = acc;
        }
        __syncthreads();
        xc_s[h][d] = xcp[h][0][d] + xcp[h][1][d] + cb[l * 128 + d];
        __syncthreads();
        // ---- theta + LUT + reduce over d: thread = n ----
        const float4* pk = packed + (size_t)(l * Dm) * NN + tid;
        float cs[2] = {0, 0}, sn[2] = {0, 0};
        for (int dd = 0; dd < 128; dd++) {
            float4 p = pk[(size_t)dd * NN];
#pragma unroll
            for (int j = 0; j < 2; j++) {
                float th = fmaf(xc_s[j][dd], p.x, p.y) + tv[j];
                int idx = ((int)floorf(th * SC)) & (RESN - 1);
                float2 scv = lut[idx];
                cs[j] = fmaf(scv.y, p.z, cs[j]);  // cos * attn_cos
                sn[j] = fmaf(scv.x, p.w, sn[j]);  // sin * attn_sin
            }
        }
#pragma unroll
        for (int j = 0; j < 2; j++) {
            cs_s[j][tid] = cs[j];
            sn_s[j][tid] = sn[j];
        }
        __syncthreads();
        // ---- proj: x_new = silu(sum @ op.T); g=0 -> xr from cs, g=1 -> xi from sn ----
        const float* wb = (h == 0 ? oprT : opiT) + l * 32768;
        const float(*ps)[256] = (h == 0) ? cs_s : sn_s;
        float acc[2] = {0, 0};
        for (int n = 0; n < 256; n++) {
            float wv = wb[n * 128 + d];
#pragma unroll
            for (int j = 0; j < 2; j++) acc[j] = fmaf(ps[j][n], wv, acc[j]);
        }
        __syncthreads();  // all reads of xs done (xc phase long past); safe to overwrite
#pragma unroll
        for (int j = 0; j < 2; j++) {
            float v = acc[j];
            xs[j][tid] = v / (1.0f + expf(-v));  // silu; note h*128+d == tid
        }
        __syncthreads();
    }
    // ---- emit bf16 A operand for final GEMM ----
#pragma unroll
    for (int j = 0; j < 2; j++) x_bf[(size_t)(t0 + j) * 256 + tid] = f2bf(xs[j][tid]);
}

// ---------------- final complex GEMM + magnitude (depth-2 pipelined, gload_lds, swizzled) -----
// 4-real-GEMM decomposition: RR=xr·WrT, II=xi·WiT, IR=xi·WrT, RI=xr·WiT
// lr = RR-II, li = IR+RI, out = sqrt(lr^2+li^2+1e-8)
// Block: 256 thr = 4 waves; tile 128t x 64v; K-chunk 32, 4 phases.
// Depth-2 prefetch: prologue stages kc=0,1; loop waits vmcnt(6) (one chunk still in
// flight), computes, then stages kc+2 into the just-freed buffer. Waits: 6,6,6,0.
__global__ void __launch_bounds__(256, 2) final_kernel(const unsigned short* __restrict__ x_bf,
                                                       const unsigned short* __restrict__ Wr_bf,
                                                       const unsigned short* __restrict__ Wi_bf,
                                                       float* __restrict__ out) {
    __shared__ unsigned short lds[2][12288];  // 2 x 24KB
    int tid = threadIdx.x;
    // bijective XCD swizzle (6288 = 8*786), t fastest within an XCD's chunk
    int wg = blockIdx.x;
    int wp = (wg & 7) * 786 + (wg >> 3);
    int vb = wp >> 3, tb = wp & 7;
    int v0 = vb * 64, t0 = tb * 128;

    int wv = tid >> 6, lane = tid & 63;
    int wm = wv >> 1, wn = wv & 1;
    int quad = lane >> 4, t16 = lane & 15;

    // ---- staging lane mapping (per-lane global source, linear LDS dest) ----
    int r_loc = lane >> 2;                       // row within a 16-row gload instruction
    int csw = (lane & 3) ^ ((lane >> 3) & 3);    // pre-swizzled source chunk (16B units)
    const unsigned short* srcA0 = x_bf + (size_t)(t0 + 32 * wv + r_loc) * 256 + csw * 8;
    const unsigned short* srcA1 = srcA0 + 16 * 256;
    int vv_ = v0 + 16 * wv + r_loc;
    if (vv_ > VV - 1) vv_ = VV - 1;              // clamp OOB v rows (dup loads, never stored)
    const unsigned short* srcWr = Wr_bf + (size_t)vv_ * 128 + csw * 8;
    const unsigned short* srcWi = Wi_bf + (size_t)vv_ * 128 + csw * 8;

    // ---- read-side constants ----
    int rsw = (t16 >> 1) & 3;
    int rdA = (wm * 64 + t16) * 32 + ((quad ^ rsw) << 3);  // +im*512; Ai region +4096
    int rdB = (wn * 32 + t16) * 32 + ((quad ^ rsw) << 3);  // +in*512; Wr +8192, Wi +10240

    f32x4_t aRR[4][2], aII[4][2], aIR[4][2], aRI[4][2];
#pragma unroll
    for (int im = 0; im < 4; im++)
#pragma unroll
        for (int in = 0; in < 2; in++) {
            aRR[im][in] = (f32x4_t){0.f, 0.f, 0.f, 0.f};
            aII[im][in] = (f32x4_t){0.f, 0.f, 0.f, 0.f};
            aIR[im][in] = (f32x4_t){0.f, 0.f, 0.f, 0.f};
            aRI[im][in] = (f32x4_t){0.f, 0.f, 0.f, 0.f};
        }

    // 6 gload_lds per wave per phase: 2x Ar, 2x Ai, 1x Wr, 1x Wi
#define STAGE(b, kc)                                                             \
    {                                                                            \
        const int ko = (kc) * 32;                                                \
        unsigned short* bb = lds[(b)];                                           \
        gload16(srcA0 + ko, bb + wv * 1024);                                     \
        gload16(srcA1 + ko, bb + wv * 1024 + 512);                               \
        gload16(srcA0 + 128 + ko, bb + 4096 + wv * 1024);                        \
        gload16(srcA1 + 128 + ko, bb + 4096 + wv * 1024 + 512);                  \
        gload16(srcWr + ko, bb + 8192 + wv * 512);                               \
        gload16(srcWi + ko, bb + 10240 + wv * 512);                              \
    }

    STAGE(0, 0);
    STAGE(1, 1);  // depth-2 prologue: 12 in flight
#pragma unroll
    for (int kc = 0; kc < 4; kc++) {
        if (kc < 3) {
            asm volatile("s_waitcnt vmcnt(6)" ::: "memory");  // chunk kc landed (kc+1 in flight)
        } else {
            asm volatile("s_waitcnt vmcnt(0)" ::: "memory");
        }
        __builtin_amdgcn_s_barrier();           // all waves' chunk-kc loads landed
        __builtin_amdgcn_sched_barrier(0);      // pin ds_reads AFTER the cross-wave sync
        const unsigned short* B = lds[kc & 1];
        s16x8_t ar[4], ai[4], fr[2], fi[2];
#pragma unroll
        for (int im = 0; im < 4; im++) {
            ar[im] = *(const s16x8_t*)(B + rdA + im * 512);
            ai[im] = *(const s16x8_t*)(B + 4096 + rdA + im * 512);
        }
#pragma unroll
        for (int in = 0; in < 2; in++) {
            fr[in] = *(const s16x8_t*)(B + 8192 + rdB + in * 512);
            fi[in] = *(const s16x8_t*)(B + 10240 + rdB + in * 512);
        }
#pragma unroll
        for (int im = 0; im < 4; im++)
#pragma unroll
            for (int in = 0; in < 2; in++) {
                aRR[im][in] = __builtin_amdgcn_mfma_f32_16x16x32_bf16(ar[im], fr[in],
                                                                      aRR[im][in], 0, 0, 0);
                aII[im][in] = __builtin_amdgcn_mfma_f32_16x16x32_bf16(ai[im], fi[in],
                                                                      aII[im][in], 0, 0, 0);
                aIR[im][in] = __builtin_amdgcn_mfma_f32_16x16x32_bf16(ai[im], fr[in],
                                                                      aIR[im][in], 0, 0, 0);
                aRI[im][in] = __builtin_amdgcn_mfma_f32_16x16x32_bf16(ar[im], fi[in],
                                                                      aRI[im][in], 0, 0, 0);
            }
        __builtin_amdgcn_s_barrier();  // all reads of this buffer done before restage
        if (kc < 2) STAGE(kc & 1, kc + 2);
    }
#undef STAGE

    // --- epilogue: complex combine + magnitude + store ---
#pragma unroll
    for (int im = 0; im < 4; im++) {
        int trow = t0 + wm * 64 + im * 16 + quad * 4;
#pragma unroll
        for (int in = 0; in < 2; in++) {
            int v = v0 + wn * 32 + in * 16 + t16;
            if (v < VV) {
#pragma unroll
                for (int r = 0; r < 4; r++) {
                    float lr = aRR[im][in][r] - aII[im][in][r];
                    float li = aIR[im][in][r] + aRI[im][in][r];
                    out[(size_t)(trow + r) * VV + v] = sqrtf(fmaf(lr, lr, fmaf(li, li, 1e-8f)));
                }
            }
        }
    }
}

extern "C" void kernel_launch(void* const* d_in, const int* in_sizes, int n_in,
                              void* d_out, int out_size, void* d_ws, size_t ws_size,
                              hipStream_t stream) {
    const int* ids   = (const int*)d_in[0];
    const float* emb = (const float*)d_in[1];
    const float* cw  = (const float*)d_in[2];
    const float* cb  = (const float*)d_in[3];
    const float* W   = (const float*)d_in[4];
    const float* Bp  = (const float*)d_in[5];
    const float* ac  = (const float*)d_in[6];
    const float* as_ = (const float*)d_in[7];
    const float* opr = (const float*)d_in[8];
    const float* opi = (const float*)d_in[9];
    const float* Wr  = (const float*)d_in[10];
    const float* Wi  = (const float*)d_in[11];
    float* out = (float*)d_out;

    char* ws = (char*)d_ws;
    float4* packed  = (float4*)(ws + (6u << 20));            // 1 MB (2x128x256 float4)
    float*  cwT     = (float*)(ws + (7u << 20));             // 256 KB
    float*  oprT    = (float*)(ws + (7u << 20) + (256u << 10));
    float*  opiT    = (float*)(ws + (7u << 20) + (512u << 10));
    float2* lutg    = (float2*)(ws + (7u << 20) + (768u << 10));  // 32 KB
    unsigned short* x_bf  = (unsigned short*)(ws + (8u  << 20));  // 512 KB (1024x256 bf16)
    unsigned short* Wr_bf = (unsigned short*)(ws + (9u  << 20));  // 12.27 MB (50257x128 bf16)
    unsigned short* Wi_bf = (unsigned short*)(ws + (22u << 20));  // 12.27 MB

    pack_kernel<<<256, 256, 0, stream>>>(W, Bp, ac, as_, cw, opr, opi,
                                         packed, cwT, oprT, opiT, lutg);
    wconv_kernel<<<(VV * Dm / 4 + 255) / 256, 256, 0, stream>>>(Wr, Wi, Wr_bf, Wi_bf);
    mid_kernel<<<TOK / 2, 256, 0, stream>>>(ids, emb, cwT, cb, packed, lutg,
                                            oprT, opiT, x_bf);
    final_kernel<<<dim3(786 * 8), 256, 0, stream>>>(x_bf, Wr_bf, Wi_bf, out);
}